// Round 5
// baseline (1960.488 us; speedup 1.0000x reference)
//
#include <hip/hip_runtime.h>
#include <stdint.h>

typedef unsigned short u16;
typedef unsigned int   u32;
typedef __attribute__((ext_vector_type(8))) __bf16 bf16x8;
typedef __attribute__((ext_vector_type(4))) float  f32x4;
typedef __attribute__((ext_vector_type(8))) u16    u16x8;
typedef __attribute__((ext_vector_type(4))) u16    u16x4;
typedef __attribute__((ext_vector_type(2))) u32    u32x2;
typedef __attribute__((ext_vector_type(2))) float  f32x2;

__device__ __forceinline__ u16 f2bf(float f) {
    u32 u = __float_as_uint(f);
    u32 r = (u + 0x7fffu + ((u >> 16) & 1u)) >> 16;   // RNE
    return (u16)r;
}
__device__ __forceinline__ float bf2f(u16 v) { return __uint_as_float(((u32)v) << 16); }
__device__ __forceinline__ float bflo(u32 v) { return __uint_as_float(v << 16); }
__device__ __forceinline__ float bfhi(u32 v) { return __uint_as_float(v & 0xffff0000u); }
__device__ __forceinline__ void gload_lds16(const void* g, void* l) {
    __builtin_amdgcn_global_load_lds((const __attribute__((address_space(1))) void*)g,
                                     (__attribute__((address_space(3))) void*)l, 16, 0, 0);
}

// ---------------------------------------------------------------- prep: weights -> bf16, bias fold
__global__ void k_prep(const float* __restrict__ W_ih, const float* __restrict__ W_hh,
                       const float* __restrict__ b_ih, const float* __restrict__ b_hh,
                       u16* __restrict__ Wf, u16* __restrict__ Whh, float* __restrict__ bsum) {
    int i = blockIdx.x * 256 + threadIdx.x;
    if (i < 768 * 512) { int o = i >> 9, k = i & 511; Wf[i] = f2bf(W_ih[o * 514 + k]); }
    if (i < 768 * 256) { Whh[i] = f2bf(W_hh[i]); }
    if (i < 768)       { bsum[i] = b_ih[i] + (i < 512 ? b_hh[i] : 0.f); }  // fold b_hh for r,z only
}

// ---------------------------------------------------------------- cast features fp32 -> bf16
__global__ void k_cast(const float* __restrict__ f, u16* __restrict__ o) {
    const size_t N8 = (size_t)262144 * 512 / 8;
    for (size_t i = (size_t)blockIdx.x * 256 + threadIdx.x; i < N8; i += (size_t)gridDim.x * 256) {
        float4 a = ((const float4*)f)[i * 2];
        float4 b = ((const float4*)f)[i * 2 + 1];
        u16x8 v;
        v[0] = f2bf(a.x); v[1] = f2bf(a.y); v[2] = f2bf(a.z); v[3] = f2bf(a.w);
        v[4] = f2bf(b.x); v[5] = f2bf(b.y); v[6] = f2bf(b.z); v[7] = f2bf(b.w);
        ((u16x8*)o)[i] = v;
    }
}

// XCD-bijective swizzle for grid 6x2048 = 12288 = 8*1536
__device__ __forceinline__ void xcd_remap(int& n0, int& m0) {
    int phys = blockIdx.x + blockIdx.y * 6;
    int logical = (phys & 7) * 1536 + (phys >> 3);
    n0 = (logical % 6) * 128;
    m0 = (logical / 6) * 128;
}

// ---------------------------------------------------------------- feature GEMM (bf16 A via global_load_lds)
__global__ __launch_bounds__(256) void k_gemm(const u16* __restrict__ featbf,
                                              const u16* __restrict__ Wf,
                                              const float* __restrict__ bsum,
                                              float* __restrict__ Gf) {
    __shared__ u16 As[128 * 64];
    __shared__ u16 Bs[128 * 64];
    const int tid = threadIdx.x;
    const int l = tid & 63, wv = tid >> 6;
    const int wr = wv >> 1, wc = wv & 1;
    const int lb = l & 15, lq = l >> 4;
    int n0, m0; xcd_remap(n0, m0);
    const int rl = l >> 3;
    const int c16 = (l & 7) * 16;
    const int sswz = (rl & 7) << 4;

    f32x4 acc[4][4] = {};

    for (int k0 = 0; k0 < 512; k0 += 64) {
        __syncthreads();
#pragma unroll
        for (int i = 0; i < 4; ++i) {
            int ci = wv * 4 + i;
            int r = ci * 8 + rl;
            const char* sa = (const char*)(featbf + (size_t)(m0 + r) * 512) + k0 * 2 + (c16 ^ sswz);
            gload_lds16(sa, (char*)As + ci * 1024);
            const char* sb = (const char*)(Wf + (size_t)(n0 + r) * 512) + k0 * 2 + (c16 ^ sswz);
            gload_lds16(sb, (char*)Bs + ci * 1024);
        }
        __syncthreads();
#pragma unroll
        for (int kc = 0; kc < 2; ++kc) {
            bf16x8 af[4], bfr[4];
#pragma unroll
            for (int mi = 0; mi < 4; ++mi) {
                int row = wr * 64 + mi * 16 + lb;
                af[mi] = *(const bf16x8*)((char*)As + row * 128 + (((kc * 32 + lq * 8) * 2) ^ ((row & 7) << 4)));
            }
#pragma unroll
            for (int ni = 0; ni < 4; ++ni) {
                int row = wc * 64 + ni * 16 + lb;
                bfr[ni] = *(const bf16x8*)((char*)Bs + row * 128 + (((kc * 32 + lq * 8) * 2) ^ ((row & 7) << 4)));
            }
#pragma unroll
            for (int mi = 0; mi < 4; ++mi)
#pragma unroll
                for (int ni = 0; ni < 4; ++ni)
                    acc[mi][ni] = __builtin_amdgcn_mfma_f32_16x16x32_bf16(af[mi], bfr[ni], acc[mi][ni], 0, 0, 0);
        }
    }
#pragma unroll
    for (int ni = 0; ni < 4; ++ni) {
        int o = n0 + wc * 64 + ni * 16 + lb;
        float bi = bsum[o];
#pragma unroll
        for (int mi = 0; mi < 4; ++mi) {
#pragma unroll
            for (int j = 0; j < 4; ++j) {
                int m = m0 + wr * 64 + mi * 16 + lq * 4 + j;
                int bb = m >> 8, tt = m & 255;
                Gf[(size_t)((tt << 10) + bb) * 768 + o] = acc[mi][ni][j] + bi;
            }
        }
    }
}

// ---------------------------------------------------------------- legacy GEMM (fp32 loads), small-ws fallback
template<typename ST>
__global__ __launch_bounds__(256) void k_gemm_legacy(const float* __restrict__ feat,
                                                     const u16* __restrict__ Wf,
                                                     const float* __restrict__ bsum,
                                                     ST* __restrict__ Gf) {
    __shared__ u16 As[128 * 64];
    __shared__ u16 Bs[128 * 64];
    const int tid = threadIdx.x;
    const int l = tid & 63, wv = tid >> 6;
    const int wr = wv >> 1, wc = wv & 1;
    const int lb = l & 15, lq = l >> 4;
    int n0, m0; xcd_remap(n0, m0);
    const int srow = tid >> 1, scol = (tid & 1) * 32;

    f32x4 acc[4][4] = {};

    for (int k0 = 0; k0 < 512; k0 += 64) {
        __syncthreads();
        const float* ga = feat + (size_t)(m0 + srow) * 512 + k0 + scol;
        const u16*   gb = Wf + (n0 + srow) * 512 + k0 + scol;
        char* arow = (char*)As + srow * 128;
        char* brow = (char*)Bs + srow * 128;
        const int swz = (srow & 7) << 4;
#pragma unroll
        for (int i = 0; i < 4; ++i) {
            float4 f0 = *(const float4*)(ga + i * 8);
            float4 f1 = *(const float4*)(ga + i * 8 + 4);
            u16x8 v;
            v[0] = f2bf(f0.x); v[1] = f2bf(f0.y); v[2] = f2bf(f0.z); v[3] = f2bf(f0.w);
            v[4] = f2bf(f1.x); v[5] = f2bf(f1.y); v[6] = f2bf(f1.z); v[7] = f2bf(f1.w);
            *(u16x8*)(arow + (((scol + i * 8) * 2) ^ swz)) = v;
            u16x8 w8 = *(const u16x8*)(gb + i * 8);
            *(u16x8*)(brow + (((scol + i * 8) * 2) ^ swz)) = w8;
        }
        __syncthreads();
#pragma unroll
        for (int kc = 0; kc < 2; ++kc) {
            bf16x8 af[4], bfr[4];
#pragma unroll
            for (int mi = 0; mi < 4; ++mi) {
                int row = wr * 64 + mi * 16 + lb;
                af[mi] = *(const bf16x8*)((char*)As + row * 128 + (((kc * 32 + lq * 8) * 2) ^ ((row & 7) << 4)));
            }
#pragma unroll
            for (int ni = 0; ni < 4; ++ni) {
                int row = wc * 64 + ni * 16 + lb;
                bfr[ni] = *(const bf16x8*)((char*)Bs + row * 128 + (((kc * 32 + lq * 8) * 2) ^ ((row & 7) << 4)));
            }
#pragma unroll
            for (int mi = 0; mi < 4; ++mi)
#pragma unroll
                for (int ni = 0; ni < 4; ++ni)
                    acc[mi][ni] = __builtin_amdgcn_mfma_f32_16x16x32_bf16(af[mi], bfr[ni], acc[mi][ni], 0, 0, 0);
        }
    }
#pragma unroll
    for (int ni = 0; ni < 4; ++ni) {
        int o = n0 + wc * 64 + ni * 16 + lb;
        float bi = bsum[o];
#pragma unroll
        for (int mi = 0; mi < 4; ++mi) {
#pragma unroll
            for (int j = 0; j < 4; ++j) {
                int m = m0 + wr * 64 + mi * 16 + lq * 4 + j;
                int bb = m >> 8, tt = m & 255;
                size_t idx = (size_t)((tt << 10) + bb) * 768 + o;
                float v = acc[mi][ni][j] + bi;
                if constexpr (sizeof(ST) == 4) Gf[idx] = v; else Gf[idx] = f2bf(v);
            }
        }
    }
}

// ---------------------------------------------------------------- recurrence v5
// 64 blocks x 16 batches, 8 waves. Wave w owns row-tiles (2w,2w+1) per gate.
// Register budget/wave (cap 256): wres kc0..4 = 120, cpack 24, acc 24, gf 24, wp 16,
// bhhn 8, coord 2, hreg 8, temps ~25  ->  ~250.
// kc5..7 PRE-FRAGMENTED in LDS (conflict-free 64x16B reads). 2 barriers/step.
// Per-lane redundant coord; dPart padded [16][10][2] (aligned, conflict-free);
// out-store delayed one step.
template<typename ST>
__global__ __launch_bounds__(512, 2) void k_rnn(const float* __restrict__ lastc,
                                                const float* __restrict__ W_ih,
                                                const float* __restrict__ bhh_g,
                                                const float* __restrict__ Wp,
                                                const float* __restrict__ bp,
                                                const u16* __restrict__ Whh,
                                                const ST* __restrict__ Gf,
                                                float* __restrict__ out) {
    __shared__ u16 Wlds[144 * 512];          // kc5,6,7 fragments: 144 slots x 64 lanes x 16B = 144 KB
    __shared__ u16 hbf[16 * 256];            // [batch][unit] bf16, XOR-swizzled rows, 8 KB
    __shared__ float dPart[16][10][2];       // [batch][wave(pad 8->10)][c], 1.25 KB

    const int tid = threadIdx.x, l = tid & 63, wv = tid >> 6;
    const int lb = l & 15, lq = l >> 4;
    const int bb = blockIdx.x << 4;
    const int swz = (lb & 7) << 4;

    // resident W fragments kc0..4 + packed coord coeffs + wp + n-gate b_hh
    bf16x8 wres[5][3][2];
    u32 cpk[3][2][4];
    float bhhn[2][4], wp0[2][4], wp1[2][4];
#pragma unroll
    for (int g = 0; g < 3; ++g)
#pragma unroll
        for (int ut = 0; ut < 2; ++ut) {
            int row = g * 256 + (2 * wv + ut) * 16 + lb;
#pragma unroll
            for (int kc = 0; kc < 5; ++kc)
                wres[kc][g][ut] = *(const bf16x8*)(Whh + row * 256 + kc * 32 + lq * 8);
#pragma unroll
            for (int j = 0; j < 4; ++j) {
                int rr = g * 256 + (2 * wv + ut) * 16 + lq * 4 + j;
                cpk[g][ut][j] = (u32)f2bf(W_ih[rr * 514 + 512]) | ((u32)f2bf(W_ih[rr * 514 + 513]) << 16);
            }
        }
#pragma unroll
    for (int ut = 0; ut < 2; ++ut)
#pragma unroll
        for (int j = 0; j < 4; ++j) {
            int u = (2 * wv + ut) * 16 + lq * 4 + j;
            bhhn[ut][j] = bhh_g[512 + u];
            wp0[ut][j] = Wp[u];
            wp1[ut][j] = Wp[256 + u];
        }

    // stage Wlds (kc5..7) pre-fragmented: slot s=(g*16+tt)*3+kcs; lane l's 16B at s*1024+l*16
    for (int i = tid; i < 36864; i += 512) {              // u32 units, 144 KB
        int s = i >> 8, r = i & 255, ll = r >> 2, e2 = r & 3;
        int g = s / 48, rem = s - g * 48, tt = rem / 3, kcs = rem - tt * 3;
        int row = g * 256 + tt * 16 + (ll & 15);
        int k = (5 + kcs) * 32 + (ll >> 4) * 8 + e2 * 2;
        ((u32*)Wlds)[i] = *(const u32*)(Whh + row * 256 + k);
    }
    for (int i = tid; i < 2048; i += 512) ((u32*)hbf)[i] = 0u;
    const float bp0 = bp[0], bp1 = bp[1];
    float cx = lastc[(bb + lb) * 2], cy = lastc[(bb + lb) * 2 + 1];   // per-lane coord (batch lb)
    __syncthreads();

    float hreg[2][4] = {};
    float prevD0 = 0.f, prevD1 = 0.f;
    const ST* gr = Gf + (size_t)(bb + lb) * 768 + lq * 4;
    const char* hrow = (const char*)hbf + lb * 512;

    for (int t = 0; t < 256; ++t) {
        // delayed out store for t-1 (ack drains over the next step)
        if (t > 0 && wv == 0 && lq == 0) {
            f32x2 d; d.x = prevD0; d.y = prevD1;
            *(f32x2*)(out + ((size_t)(bb + lb) * 256 + (t - 1)) * 2) = d;
        }

        // Gf load for this step (consumed in gates, hidden under MFMA phase)
        float gf[3][2][4];
#pragma unroll
        for (int g = 0; g < 3; ++g)
#pragma unroll
            for (int ut = 0; ut < 2; ++ut) {
                int off = g * 256 + (2 * wv + ut) * 16;
                if constexpr (sizeof(ST) == 4) {
                    float4 v = *(const float4*)(gr + off);
                    gf[g][ut][0] = v.x; gf[g][ut][1] = v.y; gf[g][ut][2] = v.z; gf[g][ut][3] = v.w;
                } else {
                    u16x4 v = *(const u16x4*)(gr + off);
#pragma unroll
                    for (int j = 0; j < 4; ++j) gf[g][ut][j] = bf2f(v[j]);
                }
            }

        // gh = W_hh @ h : kc0..4 register A-frags, kc5..7 LDS pre-fragmented
        f32x4 acc[3][2] = {};
#pragma unroll
        for (int kc = 0; kc < 5; ++kc) {
            bf16x8 hb = *(const bf16x8*)(hrow + ((kc * 64 + lq * 16) ^ swz));
#pragma unroll
            for (int g = 0; g < 3; ++g)
#pragma unroll
                for (int ut = 0; ut < 2; ++ut)
                    acc[g][ut] = __builtin_amdgcn_mfma_f32_16x16x32_bf16(wres[kc][g][ut], hb, acc[g][ut], 0, 0, 0);
        }
#pragma unroll
        for (int kcs = 0; kcs < 3; ++kcs) {
            bf16x8 hb = *(const bf16x8*)(hrow + (((5 + kcs) * 64 + lq * 16) ^ swz));
#pragma unroll
            for (int g = 0; g < 3; ++g)
#pragma unroll
                for (int ut = 0; ut < 2; ++ut) {
                    int s = (g * 16 + 2 * wv + ut) * 3 + kcs;
                    bf16x8 wl = *(const bf16x8*)((const char*)Wlds + s * 1024 + l * 16);
                    acc[g][ut] = __builtin_amdgcn_mfma_f32_16x16x32_bf16(wl, hb, acc[g][ut], 0, 0, 0);
                }
        }
        __syncthreads();   // S1: all hbf reads done -> safe to overwrite

        // gates + h update + disp partials (registers only)
        float pd0 = 0.f, pd1 = 0.f;
#pragma unroll
        for (int ut = 0; ut < 2; ++ut) {
            int ub = (2 * wv + ut) * 16 + lq * 4;
            u16 hpk[4];
#pragma unroll
            for (int j = 0; j < 4; ++j) {
                u32 cr = cpk[0][ut][j], cz = cpk[1][ut][j], cn = cpk[2][ut][j];
                float ctr = bflo(cr) * cx + bfhi(cr) * cy;
                float ctz = bflo(cz) * cx + bfhi(cz) * cy;
                float ctn = bflo(cn) * cx + bfhi(cn) * cy;
                float r = 1.f / (1.f + __expf(-(gf[0][ut][j] + ctr + acc[0][ut][j])));
                float z = 1.f / (1.f + __expf(-(gf[1][ut][j] + ctz + acc[1][ut][j])));
                float ghn = acc[2][ut][j] + bhhn[ut][j];
                float xn = gf[2][ut][j] + ctn + r * ghn;
                float e = __expf(-2.f * fabsf(xn));
                float th = (1.f - e) / (1.f + e);
                th = (xn >= 0.f) ? th : -th;
                float hn = (1.f - z) * th + z * hreg[ut][j];
                hreg[ut][j] = hn;
                pd0 += wp0[ut][j] * hn;
                pd1 += wp1[ut][j] * hn;
                hpk[j] = f2bf(hn);
            }
            u32x2 pv;
            pv.x = (u32)hpk[0] | ((u32)hpk[1] << 16);
            pv.y = (u32)hpk[2] | ((u32)hpk[3] << 16);
            *(u32x2*)((char*)hbf + lb * 512 + ((ub * 2) ^ swz)) = pv;
        }
        pd0 += __shfl_xor(pd0, 16); pd0 += __shfl_xor(pd0, 32);
        pd1 += __shfl_xor(pd1, 16); pd1 += __shfl_xor(pd1, 32);
        if (l < 16) {
            f32x2 d; d.x = pd0; d.y = pd1;
            *(f32x2*)(&dPart[l][wv][0]) = d;
        }
        __syncthreads();   // S2: h + dPart visible

        // all lanes redundantly reduce dPart for batch lb; update private coord
        {
            float4 a0 = *(const float4*)(&dPart[lb][0][0]);
            float4 a1 = *(const float4*)(&dPart[lb][2][0]);
            float4 a2 = *(const float4*)(&dPart[lb][4][0]);
            float4 a3 = *(const float4*)(&dPart[lb][6][0]);
            float d0 = bp0 + a0.x + a0.z + a1.x + a1.z + a2.x + a2.z + a3.x + a3.z;
            float d1 = bp1 + a0.y + a0.w + a1.y + a1.w + a2.y + a2.w + a3.y + a3.w;
            cx += d0; cy += d1;
            prevD0 = d0; prevD1 = d1;
        }
        // no S3: next dPart writes happen after S1(t+1), which all waves reach only
        // after completing this reduce (barrier-interval argument)
        gr += (size_t)1024 * 768;
    }
    if (wv == 0 && lq == 0) {
        f32x2 d; d.x = prevD0; d.y = prevD1;
        *(f32x2*)(out + ((size_t)(bb + lb) * 256 + 255) * 2) = d;
    }
}

// ----------------------------------------------------------------
extern "C" void kernel_launch(void* const* d_in, const int* in_sizes, int n_in,
                              void* d_out, int out_size, void* d_ws, size_t ws_size,
                              hipStream_t stream) {
    const float* feat   = (const float*)d_in[0];
    const float* lastc  = (const float*)d_in[1];
    const float* W_ih   = (const float*)d_in[2];
    const float* W_hh   = (const float*)d_in[3];
    const float* b_ih   = (const float*)d_in[4];
    const float* b_hh   = (const float*)d_in[5];
    const float* W_proj = (const float*)d_in[6];
    const float* b_proj = (const float*)d_in[7];
    float* out = (float*)d_out;

    char* ws = (char*)d_ws;
    u16*   Wf    = (u16*)ws;                                    // 768*512 bf16
    u16*   Whh   = (u16*)(ws + 786432);                         // 768*256 bf16
    float* bsum  = (float*)(ws + 786432 + 393216);              // 768 f32
    const size_t off_fb = 786432 + 393216 + 3072;
    u16*   featbf = (u16*)(ws + off_fb);                        // 262144*512 bf16
    const size_t off_gf_full = off_fb + (size_t)262144 * 512 * 2;
    const size_t need_full  = off_gf_full + (size_t)262144 * 768 * 4;
    const size_t need_tier2 = off_fb + (size_t)262144 * 768 * 4;

    k_prep<<<1536, 256, 0, stream>>>(W_ih, W_hh, b_ih, b_hh, Wf, Whh, bsum);

    if (ws_size >= need_full) {
        float* Gf = (float*)(ws + off_gf_full);
        k_cast<<<16384, 256, 0, stream>>>(feat, featbf);
        k_gemm<<<dim3(6, 2048), 256, 0, stream>>>(featbf, Wf, bsum, Gf);
        k_rnn<float><<<64, 512, 0, stream>>>(lastc, W_ih, b_hh, W_proj, b_proj, Whh, Gf, out);
    } else if (ws_size >= need_tier2) {
        float* Gf = (float*)(ws + off_fb);
        k_gemm_legacy<float><<<dim3(6, 2048), 256, 0, stream>>>(feat, Wf, bsum, Gf);
        k_rnn<float><<<64, 512, 0, stream>>>(lastc, W_ih, b_hh, W_proj, b_proj, Whh, Gf, out);
    } else {
        u16* Gf = (u16*)(ws + off_fb);
        k_gemm_legacy<u16><<<dim3(6, 2048), 256, 0, stream>>>(feat, Wf, bsum, Gf);
        k_rnn<u16><<<64, 512, 0, stream>>>(lastc, W_ih, b_hh, W_proj, b_proj, Whh, Gf, out);
    }
}

// Round 6
// 1510.911 us; speedup vs baseline: 1.2976x; 1.2976x over previous
//
#include <hip/hip_runtime.h>
#include <stdint.h>

typedef unsigned short u16;
typedef unsigned int   u32;
typedef __attribute__((ext_vector_type(8))) __bf16 bf16x8;
typedef __attribute__((ext_vector_type(4))) float  f32x4;
typedef __attribute__((ext_vector_type(8))) u16    u16x8;
typedef __attribute__((ext_vector_type(4))) u16    u16x4;
typedef __attribute__((ext_vector_type(2))) u32    u32x2;
typedef __attribute__((ext_vector_type(2))) float  f32x2;

__device__ __forceinline__ u16 f2bf(float f) {
    u32 u = __float_as_uint(f);
    u32 r = (u + 0x7fffu + ((u >> 16) & 1u)) >> 16;   // RNE
    return (u16)r;
}
__device__ __forceinline__ float bf2f(u16 v) { return __uint_as_float(((u32)v) << 16); }
__device__ __forceinline__ bf16x8 as_bf(u16x8 x) { union { u16x8 a; bf16x8 b; } u; u.a = x; return u.b; }
__device__ __forceinline__ void gload_lds16(const void* g, void* l) {
    __builtin_amdgcn_global_load_lds((const __attribute__((address_space(1))) void*)g,
                                     (__attribute__((address_space(3))) void*)l, 16, 0, 0);
}

// ---------------------------------------------------------------- prep: weights -> bf16, bias fold
__global__ void k_prep(const float* __restrict__ W_ih, const float* __restrict__ W_hh,
                       const float* __restrict__ b_ih, const float* __restrict__ b_hh,
                       u16* __restrict__ Wf, u16* __restrict__ Whh, float* __restrict__ bsum) {
    int i = blockIdx.x * 256 + threadIdx.x;
    if (i < 768 * 512) { int o = i >> 9, k = i & 511; Wf[i] = f2bf(W_ih[o * 514 + k]); }
    if (i < 768 * 256) { Whh[i] = f2bf(W_hh[i]); }
    if (i < 768)       { bsum[i] = b_ih[i] + (i < 512 ? b_hh[i] : 0.f); }  // fold b_hh for r,z only
}

// ---------------------------------------------------------------- cast features fp32 -> bf16
__global__ void k_cast(const float* __restrict__ f, u16* __restrict__ o) {
    const size_t N8 = (size_t)262144 * 512 / 8;
    for (size_t i = (size_t)blockIdx.x * 256 + threadIdx.x; i < N8; i += (size_t)gridDim.x * 256) {
        float4 a = ((const float4*)f)[i * 2];
        float4 b = ((const float4*)f)[i * 2 + 1];
        u16x8 v;
        v[0] = f2bf(a.x); v[1] = f2bf(a.y); v[2] = f2bf(a.z); v[3] = f2bf(a.w);
        v[4] = f2bf(b.x); v[5] = f2bf(b.y); v[6] = f2bf(b.z); v[7] = f2bf(b.w);
        ((u16x8*)o)[i] = v;
    }
}

// XCD-bijective swizzle for grid 6x2048 = 12288 = 8*1536
__device__ __forceinline__ void xcd_remap(int& n0, int& m0) {
    int phys = blockIdx.x + blockIdx.y * 6;
    int logical = (phys & 7) * 1536 + (phys >> 3);
    n0 = (logical % 6) * 128;
    m0 = (logical / 6) * 128;
}

// ---------------------------------------------------------------- feature GEMM (bf16 A via global_load_lds)
__global__ __launch_bounds__(256) void k_gemm(const u16* __restrict__ featbf,
                                              const u16* __restrict__ Wf,
                                              const float* __restrict__ bsum,
                                              float* __restrict__ Gf) {
    __shared__ u16 As[128 * 64];
    __shared__ u16 Bs[128 * 64];
    const int tid = threadIdx.x;
    const int l = tid & 63, wv = tid >> 6;
    const int wr = wv >> 1, wc = wv & 1;
    const int lb = l & 15, lq = l >> 4;
    int n0, m0; xcd_remap(n0, m0);
    const int rl = l >> 3;
    const int c16 = (l & 7) * 16;
    const int sswz = (rl & 7) << 4;

    f32x4 acc[4][4] = {};

    for (int k0 = 0; k0 < 512; k0 += 64) {
        __syncthreads();
#pragma unroll
        for (int i = 0; i < 4; ++i) {
            int ci = wv * 4 + i;
            int r = ci * 8 + rl;
            const char* sa = (const char*)(featbf + (size_t)(m0 + r) * 512) + k0 * 2 + (c16 ^ sswz);
            gload_lds16(sa, (char*)As + ci * 1024);
            const char* sb = (const char*)(Wf + (size_t)(n0 + r) * 512) + k0 * 2 + (c16 ^ sswz);
            gload_lds16(sb, (char*)Bs + ci * 1024);
        }
        __syncthreads();
#pragma unroll
        for (int kc = 0; kc < 2; ++kc) {
            bf16x8 af[4], bfr[4];
#pragma unroll
            for (int mi = 0; mi < 4; ++mi) {
                int row = wr * 64 + mi * 16 + lb;
                af[mi] = *(const bf16x8*)((char*)As + row * 128 + (((kc * 32 + lq * 8) * 2) ^ ((row & 7) << 4)));
            }
#pragma unroll
            for (int ni = 0; ni < 4; ++ni) {
                int row = wc * 64 + ni * 16 + lb;
                bfr[ni] = *(const bf16x8*)((char*)Bs + row * 128 + (((kc * 32 + lq * 8) * 2) ^ ((row & 7) << 4)));
            }
#pragma unroll
            for (int mi = 0; mi < 4; ++mi)
#pragma unroll
                for (int ni = 0; ni < 4; ++ni)
                    acc[mi][ni] = __builtin_amdgcn_mfma_f32_16x16x32_bf16(af[mi], bfr[ni], acc[mi][ni], 0, 0, 0);
        }
    }
#pragma unroll
    for (int ni = 0; ni < 4; ++ni) {
        int o = n0 + wc * 64 + ni * 16 + lb;
        float bi = bsum[o];
#pragma unroll
        for (int mi = 0; mi < 4; ++mi) {
#pragma unroll
            for (int j = 0; j < 4; ++j) {
                int m = m0 + wr * 64 + mi * 16 + lq * 4 + j;
                int bb = m >> 8, tt = m & 255;
                Gf[(size_t)((tt << 10) + bb) * 768 + o] = acc[mi][ni][j] + bi;
            }
        }
    }
}

// ---------------------------------------------------------------- legacy GEMM (fp32 loads), small-ws fallback
template<typename ST>
__global__ __launch_bounds__(256) void k_gemm_legacy(const float* __restrict__ feat,
                                                     const u16* __restrict__ Wf,
                                                     const float* __restrict__ bsum,
                                                     ST* __restrict__ Gf) {
    __shared__ u16 As[128 * 64];
    __shared__ u16 Bs[128 * 64];
    const int tid = threadIdx.x;
    const int l = tid & 63, wv = tid >> 6;
    const int wr = wv >> 1, wc = wv & 1;
    const int lb = l & 15, lq = l >> 4;
    int n0, m0; xcd_remap(n0, m0);
    const int srow = tid >> 1, scol = (tid & 1) * 32;

    f32x4 acc[4][4] = {};

    for (int k0 = 0; k0 < 512; k0 += 64) {
        __syncthreads();
        const float* ga = feat + (size_t)(m0 + srow) * 512 + k0 + scol;
        const u16*   gb = Wf + (n0 + srow) * 512 + k0 + scol;
        char* arow = (char*)As + srow * 128;
        char* brow = (char*)Bs + srow * 128;
        const int swz = (srow & 7) << 4;
#pragma unroll
        for (int i = 0; i < 4; ++i) {
            float4 f0 = *(const float4*)(ga + i * 8);
            float4 f1 = *(const float4*)(ga + i * 8 + 4);
            u16x8 v;
            v[0] = f2bf(f0.x); v[1] = f2bf(f0.y); v[2] = f2bf(f0.z); v[3] = f2bf(f0.w);
            v[4] = f2bf(f1.x); v[5] = f2bf(f1.y); v[6] = f2bf(f1.z); v[7] = f2bf(f1.w);
            *(u16x8*)(arow + (((scol + i * 8) * 2) ^ swz)) = v;
            u16x8 w8 = *(const u16x8*)(gb + i * 8);
            *(u16x8*)(brow + (((scol + i * 8) * 2) ^ swz)) = w8;
        }
        __syncthreads();
#pragma unroll
        for (int kc = 0; kc < 2; ++kc) {
            bf16x8 af[4], bfr[4];
#pragma unroll
            for (int mi = 0; mi < 4; ++mi) {
                int row = wr * 64 + mi * 16 + lb;
                af[mi] = *(const bf16x8*)((char*)As + row * 128 + (((kc * 32 + lq * 8) * 2) ^ ((row & 7) << 4)));
            }
#pragma unroll
            for (int ni = 0; ni < 4; ++ni) {
                int row = wc * 64 + ni * 16 + lb;
                bfr[ni] = *(const bf16x8*)((char*)Bs + row * 128 + (((kc * 32 + lq * 8) * 2) ^ ((row & 7) << 4)));
            }
#pragma unroll
            for (int mi = 0; mi < 4; ++mi)
#pragma unroll
                for (int ni = 0; ni < 4; ++ni)
                    acc[mi][ni] = __builtin_amdgcn_mfma_f32_16x16x32_bf16(af[mi], bfr[ni], acc[mi][ni], 0, 0, 0);
        }
    }
#pragma unroll
    for (int ni = 0; ni < 4; ++ni) {
        int o = n0 + wc * 64 + ni * 16 + lb;
        float bi = bsum[o];
#pragma unroll
        for (int mi = 0; mi < 4; ++mi) {
#pragma unroll
            for (int j = 0; j < 4; ++j) {
                int m = m0 + wr * 64 + mi * 16 + lq * 4 + j;
                int bb = m >> 8, tt = m & 255;
                size_t idx = (size_t)((tt << 10) + bb) * 768 + o;
                float v = acc[mi][ni][j] + bi;
                if constexpr (sizeof(ST) == 4) Gf[idx] = v; else Gf[idx] = f2bf(v);
            }
        }
    }
}

// ---------------------------------------------------------------- recurrence v6 = R2 (886us, spill-free)
// + prefrag Wlds (conflict-free reads) + delayed out-store. NOTHING else changed.
// 64 blocks x 16 batches, 8 waves; wave w owns row-tiles (2w,2w+1) per gate.
// W_hh kc0..4 resident (120 regs), kc5..7 pre-fragmented in LDS (144 KB).
// Coord folded via k-extension MFMA (k=256:cx, 257:cy); n-gate coord in separate acc.
template<typename ST>
__global__ __launch_bounds__(512, 2) void k_rnn(const float* __restrict__ lastc,
                                                const float* __restrict__ W_ih,
                                                const float* __restrict__ bhh_g,
                                                const float* __restrict__ Wp,
                                                const float* __restrict__ bp,
                                                const u16* __restrict__ Whh,
                                                const ST* __restrict__ Gf,
                                                float* __restrict__ out) {
    __shared__ u16 Wlds[144 * 512];          // kc5..7 fragments: 144 slots x 64 lanes x 16B = 144 KB
    __shared__ u16 hbf[16 * 320];            // [batch][k 0..319]: h(0..255) + ext(256..319), XOR-swizzled
    __shared__ float wpL[256 * 2];           // [u][c]
    __shared__ float coordL[16 * 2];
    __shared__ float dPart[8 * 16 * 2];

    const int tid = threadIdx.x, l = tid & 63, wv = tid >> 6;
    const int lb = l & 15, lq = l >> 4;
    const int bb = blockIdx.x << 4;
    const int swz = (lb & 7) << 4;

    // resident W fragments kc0..4 + coord-ext fragments + n-gate b_hh
    bf16x8 wres[5][3][2];
    bf16x8 wcf[3][2];
    float bhhn[2][4];
#pragma unroll
    for (int g = 0; g < 3; ++g)
#pragma unroll
        for (int ut = 0; ut < 2; ++ut) {
            int row = g * 256 + (2 * wv + ut) * 16 + lb;
#pragma unroll
            for (int kc = 0; kc < 5; ++kc)
                wres[kc][g][ut] = *(const bf16x8*)(Whh + row * 256 + kc * 32 + lq * 8);
            u16x8 cf = {0, 0, 0, 0, 0, 0, 0, 0};
            if (lq == 0) {
                cf[0] = f2bf(W_ih[row * 514 + 512]);
                cf[1] = f2bf(W_ih[row * 514 + 513]);
            }
            wcf[g][ut] = as_bf(cf);
        }
#pragma unroll
    for (int ut = 0; ut < 2; ++ut)
#pragma unroll
        for (int j = 0; j < 4; ++j)
            bhhn[ut][j] = bhh_g[512 + (2 * wv + ut) * 16 + lq * 4 + j];

    // stage Wlds (kc5..7) PRE-FRAGMENTED: slot s=(g*16+tt)*3+kcs; lane l's 16B at s*1024+l*16
    for (int i = tid; i < 36864; i += 512) {              // u32 units, 144 KB
        int s = i >> 8, r = i & 255, ll = r >> 2, e2 = r & 3;
        int g = s / 48, rem = s - g * 48, tt = rem / 3, kcs = rem - tt * 3;
        int row = g * 256 + tt * 16 + (ll & 15);
        int k = (5 + kcs) * 32 + (ll >> 4) * 8 + e2 * 2;
        ((u32*)Wlds)[i] = *(const u32*)(Whh + row * 256 + k);
    }
    for (int i = tid; i < 16 * 320 / 2; i += 512) ((u32*)hbf)[i] = 0u;
    if (tid < 256) { wpL[tid * 2] = Wp[tid]; wpL[tid * 2 + 1] = Wp[256 + tid]; }
    float bpc = (tid < 32) ? bp[tid & 1] : 0.f;
    __syncthreads();
    if (tid < 32) {
        int b = tid >> 1, c = tid & 1;
        float cc = lastc[(bb + b) * 2 + c];
        coordL[b * 2 + c] = cc;
        *(u16*)((char*)hbf + b * 640 + 512 + ((c * 2) ^ ((b & 7) << 4))) = f2bf(cc);
    }
    __syncthreads();

    float hreg[2][4] = {};
    float prevD = 0.f;
    const ST* gr = Gf + (size_t)(bb + lb) * 768 + lq * 4;
    const char* hrow = (const char*)hbf + lb * 640;

    for (int t = 0; t < 256; ++t) {
        // delayed out store for t-1: issued here, drains at S1 (~2000 cyc later)
        if (t > 0 && tid < 32)
            out[((size_t)(bb + (tid >> 1)) * 256 + (t - 1)) * 2 + (tid & 1)] = prevD;

        // Gf prefetch (HBM latency hidden under MFMA phase, drained at S1)
        float gf[3][2][4];
#pragma unroll
        for (int g = 0; g < 3; ++g)
#pragma unroll
            for (int ut = 0; ut < 2; ++ut) {
                int off = g * 256 + (2 * wv + ut) * 16;
                if constexpr (sizeof(ST) == 4) {
                    float4 v = *(const float4*)(gr + off);
                    gf[g][ut][0] = v.x; gf[g][ut][1] = v.y; gf[g][ut][2] = v.z; gf[g][ut][3] = v.w;
                } else {
                    u16x4 v = *(const u16x4*)(gr + off);
#pragma unroll
                    for (int j = 0; j < 4; ++j) gf[g][ut][j] = bf2f(v[j]);
                }
            }

        // gh = W_hh @ h (+ coord via k-ext)
        f32x4 acc[3][2] = {};
        f32x4 accC[2] = {};
#pragma unroll
        for (int kc = 0; kc < 5; ++kc) {
            bf16x8 hb = *(const bf16x8*)(hrow + ((kc * 64 + lq * 16) ^ swz));
#pragma unroll
            for (int g = 0; g < 3; ++g)
#pragma unroll
                for (int ut = 0; ut < 2; ++ut)
                    acc[g][ut] = __builtin_amdgcn_mfma_f32_16x16x32_bf16(wres[kc][g][ut], hb, acc[g][ut], 0, 0, 0);
        }
#pragma unroll
        for (int kcs = 0; kcs < 3; ++kcs) {
            bf16x8 hb = *(const bf16x8*)(hrow + (((5 + kcs) * 64 + lq * 16) ^ swz));
#pragma unroll
            for (int g = 0; g < 3; ++g)
#pragma unroll
                for (int ut = 0; ut < 2; ++ut) {
                    int s = (g * 16 + 2 * wv + ut) * 3 + kcs;
                    bf16x8 wl = *(const bf16x8*)((const char*)Wlds + s * 1024 + l * 16);
                    acc[g][ut] = __builtin_amdgcn_mfma_f32_16x16x32_bf16(wl, hb, acc[g][ut], 0, 0, 0);
                }
        }
        {
            bf16x8 hbE = *(const bf16x8*)(hrow + 512 + ((lq * 16) ^ swz));
#pragma unroll
            for (int ut = 0; ut < 2; ++ut) {
                acc[0][ut] = __builtin_amdgcn_mfma_f32_16x16x32_bf16(wcf[0][ut], hbE, acc[0][ut], 0, 0, 0);
                acc[1][ut] = __builtin_amdgcn_mfma_f32_16x16x32_bf16(wcf[1][ut], hbE, acc[1][ut], 0, 0, 0);
                accC[ut]   = __builtin_amdgcn_mfma_f32_16x16x32_bf16(wcf[2][ut], hbE, accC[ut],   0, 0, 0);
            }
        }
        __syncthreads();   // S1: all hbf reads done -> safe to overwrite

        // gates + h update + disp partials (registers)
        float pd0 = 0.f, pd1 = 0.f;
#pragma unroll
        for (int ut = 0; ut < 2; ++ut) {
            int ub = (2 * wv + ut) * 16 + lq * 4;
            float4 wpa = *(const float4*)(wpL + ub * 2);
            float4 wpb = *(const float4*)(wpL + ub * 2 + 4);
            u16 hpk[4];
#pragma unroll
            for (int j = 0; j < 4; ++j) {
                float r = 1.f / (1.f + __expf(-(gf[0][ut][j] + acc[0][ut][j])));
                float z = 1.f / (1.f + __expf(-(gf[1][ut][j] + acc[1][ut][j])));
                float ghn = acc[2][ut][j] + bhhn[ut][j];
                float xn = gf[2][ut][j] + accC[ut][j] + r * ghn;
                float e = __expf(-2.f * fabsf(xn));
                float th = (1.f - e) / (1.f + e);
                th = (xn >= 0.f) ? th : -th;
                float hn = (1.f - z) * th + z * hreg[ut][j];
                hreg[ut][j] = hn;
                float w0 = (j == 0) ? wpa.x : (j == 1) ? wpa.z : (j == 2) ? wpb.x : wpb.z;
                float w1 = (j == 0) ? wpa.y : (j == 1) ? wpa.w : (j == 2) ? wpb.y : wpb.w;
                pd0 += w0 * hn;
                pd1 += w1 * hn;
                hpk[j] = f2bf(hn);
            }
            u32x2 pv;
            pv.x = (u32)hpk[0] | ((u32)hpk[1] << 16);
            pv.y = (u32)hpk[2] | ((u32)hpk[3] << 16);
            *(u32x2*)((char*)hbf + lb * 640 + ((ub * 2) ^ swz)) = pv;
        }
        pd0 += __shfl_xor(pd0, 16); pd0 += __shfl_xor(pd0, 32);
        pd1 += __shfl_xor(pd1, 16); pd1 += __shfl_xor(pd1, 32);
        if (l < 16) { dPart[(wv * 16 + l) * 2] = pd0; dPart[(wv * 16 + l) * 2 + 1] = pd1; }
        __syncthreads();   // S2: hbf + dPart written

        if (tid < 32) {
            int b = tid >> 1, c = tid & 1;
            float d = bpc;
#pragma unroll
            for (int w8 = 0; w8 < 8; ++w8) d += dPart[(w8 * 16 + b) * 2 + c];
            prevD = d;                         // store issued at top of next step
            float nc = coordL[b * 2 + c] + d;
            coordL[b * 2 + c] = nc;
            *(u16*)((char*)hbf + b * 640 + 512 + ((c * 2) ^ ((b & 7) << 4))) = f2bf(nc);
        }
        __syncthreads();   // S3: coord ext updated
        gr += (size_t)1024 * 768;
    }
    if (tid < 32)
        out[((size_t)(bb + (tid >> 1)) * 256 + 255) * 2 + (tid & 1)] = prevD;
}

// ----------------------------------------------------------------
extern "C" void kernel_launch(void* const* d_in, const int* in_sizes, int n_in,
                              void* d_out, int out_size, void* d_ws, size_t ws_size,
                              hipStream_t stream) {
    const float* feat   = (const float*)d_in[0];
    const float* lastc  = (const float*)d_in[1];
    const float* W_ih   = (const float*)d_in[2];
    const float* W_hh   = (const float*)d_in[3];
    const float* b_ih   = (const float*)d_in[4];
    const float* b_hh   = (const float*)d_in[5];
    const float* W_proj = (const float*)d_in[6];
    const float* b_proj = (const float*)d_in[7];
    float* out = (float*)d_out;

    char* ws = (char*)d_ws;
    u16*   Wf    = (u16*)ws;                                    // 768*512 bf16
    u16*   Whh   = (u16*)(ws + 786432);                         // 768*256 bf16
    float* bsum  = (float*)(ws + 786432 + 393216);              // 768 f32
    const size_t off_fb = 786432 + 393216 + 3072;
    u16*   featbf = (u16*)(ws + off_fb);                        // 262144*512 bf16
    const size_t off_gf_full = off_fb + (size_t)262144 * 512 * 2;
    const size_t need_full  = off_gf_full + (size_t)262144 * 768 * 4;
    const size_t need_tier2 = off_fb + (size_t)262144 * 768 * 4;

    k_prep<<<1536, 256, 0, stream>>>(W_ih, W_hh, b_ih, b_hh, Wf, Whh, bsum);

    if (ws_size >= need_full) {
        float* Gf = (float*)(ws + off_gf_full);
        k_cast<<<16384, 256, 0, stream>>>(feat, featbf);
        k_gemm<<<dim3(6, 2048), 256, 0, stream>>>(featbf, Wf, bsum, Gf);
        k_rnn<float><<<64, 512, 0, stream>>>(lastc, W_ih, b_hh, W_proj, b_proj, Whh, Gf, out);
    } else if (ws_size >= need_tier2) {
        float* Gf = (float*)(ws + off_fb);
        k_gemm_legacy<float><<<dim3(6, 2048), 256, 0, stream>>>(feat, Wf, bsum, Gf);
        k_rnn<float><<<64, 512, 0, stream>>>(lastc, W_ih, b_hh, W_proj, b_proj, Whh, Gf, out);
    } else {
        u16* Gf = (u16*)(ws + off_fb);
        k_gemm_legacy<u16><<<dim3(6, 2048), 256, 0, stream>>>(feat, Wf, bsum, Gf);
        k_rnn<u16><<<64, 512, 0, stream>>>(lastc, W_ih, b_hh, W_proj, b_proj, Whh, Gf, out);
    }
}